// Round 2
// baseline (544.236 us; speedup 1.0000x reference)
//
#include <hip/hip_runtime.h>

#define N_NODES 50000
#define N_EDGES 600000
#define XS_STRIDE 132   // 128 floats per row + 4 pad (16B) to break bank alignment

// ---------------- graph build ----------------

__global__ void init_counts(int* __restrict__ cnt, int* __restrict__ fill) {
    int i = blockIdx.x * blockDim.x + threadIdx.x;
    if (i < N_NODES) { cnt[i] = 0; fill[i] = 0; }
}

__global__ void count_edges(const int* __restrict__ dst, int* __restrict__ cnt) {
    int e = blockIdx.x * blockDim.x + threadIdx.x;
    if (e < N_EDGES) atomicAdd(&cnt[dst[e]], 1);
}

__global__ void compute_dinv(const int* __restrict__ cnt, float* __restrict__ dinv) {
    int i = blockIdx.x * blockDim.x + threadIdx.x;
    if (i < N_NODES) dinv[i] = 1.0f / sqrtf((float)(cnt[i] + 1));  // +1 self-loop
}

// single-workgroup scan of cnt -> exclusive rowptr (N=50000, 49 chunks of 1024)
__global__ void scan_rowptr(const int* __restrict__ cnt, int* __restrict__ rowptr) {
    __shared__ int sdata[1024];
    __shared__ int soffset;
    int tid = threadIdx.x;
    if (tid == 0) { soffset = 0; rowptr[0] = 0; }
    __syncthreads();
    for (int base = 0; base < N_NODES; base += 1024) {
        int i = base + tid;
        int v = (i < N_NODES) ? cnt[i] : 0;
        sdata[tid] = v;
        __syncthreads();
        for (int s = 1; s < 1024; s <<= 1) {
            int t = (tid >= s) ? sdata[tid - s] : 0;
            __syncthreads();
            sdata[tid] += t;
            __syncthreads();
        }
        if (i < N_NODES) rowptr[i + 1] = soffset + sdata[tid];
        int total = sdata[1023];
        __syncthreads();
        if (tid == 0) soffset += total;
        __syncthreads();
    }
}

__global__ void csr_fill(const int* __restrict__ srcArr, const int* __restrict__ dstArr,
                         const int* __restrict__ rowptr, int* __restrict__ fill,
                         int* __restrict__ col, float* __restrict__ colw,
                         const float* __restrict__ dinv) {
    int e = blockIdx.x * blockDim.x + threadIdx.x;
    if (e < N_EDGES) {
        int d = dstArr[e];
        int s = srcArr[e];
        int pos = rowptr[d] + atomicAdd(&fill[d], 1);
        col[pos] = s;
        colw[pos] = dinv[s];   // pre-multiplied dinv[src]
    }
}

// ---------------- dense GEMM [N,128]@[128,128] ----------------
// block = 256 threads, tile = 64 rows x 128 cols, micro-tile 4x8.
// x staged in LDS (row stride 132 floats = 128 + 16B pad),
// W streamed from global (64KB, L1/L2-resident across all blocks).

__global__ __launch_bounds__(256) void gemm128(const float* __restrict__ X,
                                               const float* __restrict__ W,
                                               float* __restrict__ T) {
    __shared__ float xs[64 * XS_STRIDE];
    int tid = threadIdx.x;
    int row0 = blockIdx.x * 64;

    // stage 64x128 floats = 2048 float4, 8 per thread
    #pragma unroll
    for (int i = 0; i < 8; ++i) {
        int fi = tid + i * 256;        // 0..2047
        int r  = fi >> 5;              // 32 float4 per row
        int c4 = (fi & 31) << 2;       // float offset within row: 0..124
        float4 v = make_float4(0.f, 0.f, 0.f, 0.f);
        int rg = row0 + r;
        if (rg < N_NODES) v = *(const float4*)&X[(size_t)rg * 128 + c4];
        float* p = &xs[r * XS_STRIDE + c4];
        p[0] = v.x; p[1] = v.y; p[2] = v.z; p[3] = v.w;
    }
    __syncthreads();

    int cg = tid & 15, rg = tid >> 4;
    int c0 = cg * 8, r0 = rg * 4;
    float acc[4][8];
    #pragma unroll
    for (int i = 0; i < 4; ++i)
        #pragma unroll
        for (int j = 0; j < 8; ++j) acc[i][j] = 0.f;

    for (int k0 = 0; k0 < 128; k0 += 4) {
        float4 a[4];
        #pragma unroll
        for (int i = 0; i < 4; ++i) a[i] = *(const float4*)&xs[(r0 + i) * XS_STRIDE + k0];
        #pragma unroll
        for (int kk = 0; kk < 4; ++kk) {
            float4 blo = *(const float4*)&W[(k0 + kk) * 128 + c0];
            float4 bhi = *(const float4*)&W[(k0 + kk) * 128 + c0 + 4];
            float bv0 = blo.x, bv1 = blo.y, bv2 = blo.z, bv3 = blo.w;
            float bv4 = bhi.x, bv5 = bhi.y, bv6 = bhi.z, bv7 = bhi.w;
            #pragma unroll
            for (int i = 0; i < 4; ++i) {
                float av = (kk == 0) ? a[i].x : (kk == 1) ? a[i].y : (kk == 2) ? a[i].z : a[i].w;
                acc[i][0] += av * bv0;  acc[i][1] += av * bv1;
                acc[i][2] += av * bv2;  acc[i][3] += av * bv3;
                acc[i][4] += av * bv4;  acc[i][5] += av * bv5;
                acc[i][6] += av * bv6;  acc[i][7] += av * bv7;
            }
        }
    }

    #pragma unroll
    for (int i = 0; i < 4; ++i) {
        int r = row0 + r0 + i;
        if (r < N_NODES) {
            float4 o0 = make_float4(acc[i][0], acc[i][1], acc[i][2], acc[i][3]);
            float4 o1 = make_float4(acc[i][4], acc[i][5], acc[i][6], acc[i][7]);
            *(float4*)&T[(size_t)r * 128 + c0]     = o0;
            *(float4*)&T[(size_t)r * 128 + c0 + 4] = o1;
        }
    }
}

// ---------------- aggregation: out[v] = relu(dinv[v]*(sum dinv[s]*T[s] + dinv[v]*T[v]) + b) ----------------
// one 128-thread block per node; thread j owns feature j. Gather-only, no float atomics.

__global__ void gcn_aggregate(const float* __restrict__ T, const int* __restrict__ rowptr,
                              const int* __restrict__ col, const float* __restrict__ colw,
                              const float* __restrict__ dinv, const float* __restrict__ bias,
                              float* __restrict__ out) {
    int v = blockIdx.x;
    int j = threadIdx.x;
    float dv = dinv[v];
    float acc = dv * T[(size_t)v * 128 + j];   // self-loop term (gets *dv again below)
    int beg = rowptr[v], end = rowptr[v + 1];
    for (int e = beg; e < end; ++e) {
        int s = col[e];
        float w = colw[e];
        acc += w * T[(size_t)s * 128 + j];
    }
    float r = fmaf(dv, acc, bias[j]);
    out[(size_t)v * 128 + j] = fmaxf(r, 0.f);
}

// ---------------- final linear [N,128]@[128,32] + bias ----------------

__global__ void gemm_final(const float* __restrict__ H, const float* __restrict__ Wl,
                           const float* __restrict__ bl, float* __restrict__ out) {
    int tid = threadIdx.x;
    int v = blockIdx.x * 8 + (tid >> 5);
    int c = tid & 31;
    if (v >= N_NODES) return;
    float acc = 0.f;
    for (int k0 = 0; k0 < 128; k0 += 4) {
        float4 h = *(const float4*)&H[(size_t)v * 128 + k0];
        acc = fmaf(h.x, Wl[(k0 + 0) * 32 + c], acc);
        acc = fmaf(h.y, Wl[(k0 + 1) * 32 + c], acc);
        acc = fmaf(h.z, Wl[(k0 + 2) * 32 + c], acc);
        acc = fmaf(h.w, Wl[(k0 + 3) * 32 + c], acc);
    }
    out[(size_t)v * 32 + c] = acc + bl[c];
}

// ---------------- launch ----------------

extern "C" void kernel_launch(void* const* d_in, const int* in_sizes, int n_in,
                              void* d_out, int out_size, void* d_ws, size_t ws_size,
                              hipStream_t stream) {
    const float* x      = (const float*)d_in[0];
    const int*   ei     = (const int*)d_in[1];
    const int*   srcArr = ei;             // edge_index[0]
    const int*   dstArr = ei + N_EDGES;   // edge_index[1]
    const float* W1 = (const float*)d_in[2];
    const float* b1 = (const float*)d_in[3];
    const float* W2 = (const float*)d_in[4];
    const float* b2 = (const float*)d_in[5];
    const float* W3 = (const float*)d_in[6];
    const float* b3 = (const float*)d_in[7];
    const float* Wl = (const float*)d_in[8];
    const float* bl = (const float*)d_in[9];
    float* out = (float*)d_out;

    // workspace layout (~57 MB)
    float* bufA   = (float*)d_ws;                       // N*128
    float* bufB   = bufA + (size_t)N_NODES * 128;       // N*128
    float* dinv   = bufB + (size_t)N_NODES * 128;       // N
    float* colw   = dinv + N_NODES;                     // E
    int*   cnt    = (int*)(colw + N_EDGES);             // N
    int*   fill   = cnt + N_NODES;                      // N
    int*   rowptr = fill + N_NODES;                     // N+1
    int*   col    = rowptr + (N_NODES + 1);             // E

    init_counts <<<(N_NODES + 255) / 256, 256, 0, stream>>>(cnt, fill);
    count_edges <<<(N_EDGES + 255) / 256, 256, 0, stream>>>(dstArr, cnt);
    compute_dinv<<<(N_NODES + 255) / 256, 256, 0, stream>>>(cnt, dinv);
    scan_rowptr <<<1, 1024, 0, stream>>>(cnt, rowptr);
    csr_fill    <<<(N_EDGES + 255) / 256, 256, 0, stream>>>(srcArr, dstArr, rowptr, fill, col, colw, dinv);

    gemm128<<<(N_NODES + 63) / 64, 256, 0, stream>>>(x, W1, bufA);
    gcn_aggregate<<<N_NODES, 128, 0, stream>>>(bufA, rowptr, col, colw, dinv, b1, bufB);
    gemm128<<<(N_NODES + 63) / 64, 256, 0, stream>>>(bufB, W2, bufA);
    gcn_aggregate<<<N_NODES, 128, 0, stream>>>(bufA, rowptr, col, colw, dinv, b2, bufB);
    gemm128<<<(N_NODES + 63) / 64, 256, 0, stream>>>(bufB, W3, bufA);
    gcn_aggregate<<<N_NODES, 128, 0, stream>>>(bufA, rowptr, col, colw, dinv, b3, bufB);
    gemm_final<<<(N_NODES + 7) / 8, 256, 0, stream>>>(bufB, Wl, bl, out);
}

// Round 4
// 362.242 us; speedup vs baseline: 1.5024x; 1.5024x over previous
//
#include <hip/hip_runtime.h>

#define N_NODES 50000
#define N_EDGES 600000
#define XS_STRIDE 132   // 128 floats per row + 4 pad to break bank alignment

// ---------------- graph build ----------------

__global__ void count_edges(const int* __restrict__ dst, int* __restrict__ cnt) {
    int e = blockIdx.x * blockDim.x + threadIdx.x;
    if (e < N_EDGES) atomicAdd(&cnt[dst[e]], 1);
}

// Reserve CSR slots: start[v] = atomicAdd(total, cnt[v]). Order of rows in the
// col/colw arrays is nondeterministic but the edge SET per row is exact; the
// aggregation sum is order-insensitive to ~1e-6 (threshold 2e-3).
__global__ void reserve_rows(const int* __restrict__ cnt, int* __restrict__ start,
                             int* __restrict__ total, float* __restrict__ dinv) {
    int i = blockIdx.x * blockDim.x + threadIdx.x;
    if (i < N_NODES) {
        int c = cnt[i];
        start[i] = atomicAdd(total, c);
        dinv[i] = 1.0f / sqrtf((float)(c + 1));   // +1 self-loop
    }
}

__global__ void csr_fill(const int* __restrict__ srcArr, const int* __restrict__ dstArr,
                         const int* __restrict__ start, int* __restrict__ fill,
                         int* __restrict__ col, float* __restrict__ colw,
                         const float* __restrict__ dinv) {
    int e = blockIdx.x * blockDim.x + threadIdx.x;
    if (e < N_EDGES) {
        int d = dstArr[e];
        int s = srcArr[e];
        int pos = start[d] + atomicAdd(&fill[d], 1);
        col[pos] = s;
        colw[pos] = dinv[s];   // pre-multiplied dinv[src]
    }
}

// ---------------- dense GEMM [N,128]@[128,128] ----------------
// block = 256 threads, tile = 64 rows x 128 cols, micro-tile 4x8.

__global__ __launch_bounds__(256) void gemm128(const float* __restrict__ X,
                                               const float* __restrict__ W,
                                               float* __restrict__ T) {
    __shared__ float xs[64 * XS_STRIDE];
    int tid = threadIdx.x;
    int row0 = blockIdx.x * 64;

    #pragma unroll
    for (int i = 0; i < 8; ++i) {
        int fi = tid + i * 256;
        int r  = fi >> 5;
        int c4 = (fi & 31) << 2;
        float4 v = make_float4(0.f, 0.f, 0.f, 0.f);
        int rg = row0 + r;
        if (rg < N_NODES) v = *(const float4*)&X[(size_t)rg * 128 + c4];
        float* p = &xs[r * XS_STRIDE + c4];
        p[0] = v.x; p[1] = v.y; p[2] = v.z; p[3] = v.w;
    }
    __syncthreads();

    int cg = tid & 15, rg = tid >> 4;
    int c0 = cg * 8, r0 = rg * 4;
    float acc[4][8];
    #pragma unroll
    for (int i = 0; i < 4; ++i)
        #pragma unroll
        for (int j = 0; j < 8; ++j) acc[i][j] = 0.f;

    for (int k0 = 0; k0 < 128; k0 += 4) {
        float4 a[4];
        #pragma unroll
        for (int i = 0; i < 4; ++i) a[i] = *(const float4*)&xs[(r0 + i) * XS_STRIDE + k0];
        #pragma unroll
        for (int kk = 0; kk < 4; ++kk) {
            float4 blo = *(const float4*)&W[(k0 + kk) * 128 + c0];
            float4 bhi = *(const float4*)&W[(k0 + kk) * 128 + c0 + 4];
            #pragma unroll
            for (int i = 0; i < 4; ++i) {
                float av = (kk == 0) ? a[i].x : (kk == 1) ? a[i].y : (kk == 2) ? a[i].z : a[i].w;
                acc[i][0] = fmaf(av, blo.x, acc[i][0]);
                acc[i][1] = fmaf(av, blo.y, acc[i][1]);
                acc[i][2] = fmaf(av, blo.z, acc[i][2]);
                acc[i][3] = fmaf(av, blo.w, acc[i][3]);
                acc[i][4] = fmaf(av, bhi.x, acc[i][4]);
                acc[i][5] = fmaf(av, bhi.y, acc[i][5]);
                acc[i][6] = fmaf(av, bhi.z, acc[i][6]);
                acc[i][7] = fmaf(av, bhi.w, acc[i][7]);
            }
        }
    }

    #pragma unroll
    for (int i = 0; i < 4; ++i) {
        int r = row0 + r0 + i;
        if (r < N_NODES) {
            float4 o0 = make_float4(acc[i][0], acc[i][1], acc[i][2], acc[i][3]);
            float4 o1 = make_float4(acc[i][4], acc[i][5], acc[i][6], acc[i][7]);
            *(float4*)&T[(size_t)r * 128 + c0]     = o0;
            *(float4*)&T[(size_t)r * 128 + c0 + 4] = o1;
        }
    }
}

// ---------------- aggregation ----------------
// out[v] = relu(dinv[v]*(sum_e colw[e]*T[col[e]] + dinv[v]*T[v]) + b)
// 32 lanes per node (float4 per lane), 8 nodes per 256-thread block.
// grid = 50000/8 = 6250 exactly -> no bounds checks.

__global__ __launch_bounds__(256) void gcn_aggregate(
        const float* __restrict__ T, const int* __restrict__ start,
        const int* __restrict__ cnt, const int* __restrict__ col,
        const float* __restrict__ colw, const float* __restrict__ dinv,
        const float* __restrict__ bias, float* __restrict__ out) {
    int tid = threadIdx.x;
    int g = tid >> 5, lane = tid & 31;
    int v = blockIdx.x * 8 + g;
    int f4 = lane << 2;
    float dv = dinv[v];
    const float4 tv = *(const float4*)&T[(size_t)v * 128 + f4];
    float4 acc = make_float4(dv * tv.x, dv * tv.y, dv * tv.z, dv * tv.w);
    int beg = start[v], end = beg + cnt[v];
    int e = beg;
    for (; e + 2 <= end; e += 2) {
        int s0 = col[e], s1 = col[e + 1];
        float w0 = colw[e], w1 = colw[e + 1];
        const float4 t0 = *(const float4*)&T[(size_t)s0 * 128 + f4];
        const float4 t1 = *(const float4*)&T[(size_t)s1 * 128 + f4];
        acc.x = fmaf(w0, t0.x, fmaf(w1, t1.x, acc.x));
        acc.y = fmaf(w0, t0.y, fmaf(w1, t1.y, acc.y));
        acc.z = fmaf(w0, t0.z, fmaf(w1, t1.z, acc.z));
        acc.w = fmaf(w0, t0.w, fmaf(w1, t1.w, acc.w));
    }
    if (e < end) {
        int s0 = col[e];
        float w0 = colw[e];
        const float4 t0 = *(const float4*)&T[(size_t)s0 * 128 + f4];
        acc.x = fmaf(w0, t0.x, acc.x);
        acc.y = fmaf(w0, t0.y, acc.y);
        acc.z = fmaf(w0, t0.z, acc.z);
        acc.w = fmaf(w0, t0.w, acc.w);
    }
    const float4 b4 = *(const float4*)&bias[f4];
    float4 r;
    r.x = fmaxf(fmaf(dv, acc.x, b4.x), 0.f);
    r.y = fmaxf(fmaf(dv, acc.y, b4.y), 0.f);
    r.z = fmaxf(fmaf(dv, acc.z, b4.z), 0.f);
    r.w = fmaxf(fmaf(dv, acc.w, b4.w), 0.f);
    *(float4*)&out[(size_t)v * 128 + f4] = r;
}

// Layer-3 aggregate fused with the final [128,32] linear: h3 row staged in LDS,
// each lane then computes one output column.

__global__ __launch_bounds__(256) void gcn_aggregate_final(
        const float* __restrict__ T, const int* __restrict__ start,
        const int* __restrict__ cnt, const int* __restrict__ col,
        const float* __restrict__ colw, const float* __restrict__ dinv,
        const float* __restrict__ bias, const float* __restrict__ Wl,
        const float* __restrict__ bl, float* __restrict__ out32) {
    __shared__ float sh[8 * 128];
    int tid = threadIdx.x;
    int g = tid >> 5, lane = tid & 31;
    int v = blockIdx.x * 8 + g;
    int f4 = lane << 2;
    float dv = dinv[v];
    const float4 tv = *(const float4*)&T[(size_t)v * 128 + f4];
    float4 acc = make_float4(dv * tv.x, dv * tv.y, dv * tv.z, dv * tv.w);
    int beg = start[v], end = beg + cnt[v];
    int e = beg;
    for (; e + 2 <= end; e += 2) {
        int s0 = col[e], s1 = col[e + 1];
        float w0 = colw[e], w1 = colw[e + 1];
        const float4 t0 = *(const float4*)&T[(size_t)s0 * 128 + f4];
        const float4 t1 = *(const float4*)&T[(size_t)s1 * 128 + f4];
        acc.x = fmaf(w0, t0.x, fmaf(w1, t1.x, acc.x));
        acc.y = fmaf(w0, t0.y, fmaf(w1, t1.y, acc.y));
        acc.z = fmaf(w0, t0.z, fmaf(w1, t1.z, acc.z));
        acc.w = fmaf(w0, t0.w, fmaf(w1, t1.w, acc.w));
    }
    if (e < end) {
        int s0 = col[e];
        float w0 = colw[e];
        const float4 t0 = *(const float4*)&T[(size_t)s0 * 128 + f4];
        acc.x = fmaf(w0, t0.x, acc.x);
        acc.y = fmaf(w0, t0.y, acc.y);
        acc.z = fmaf(w0, t0.z, acc.z);
        acc.w = fmaf(w0, t0.w, acc.w);
    }
    const float4 b4 = *(const float4*)&bias[f4];
    float4 r;
    r.x = fmaxf(fmaf(dv, acc.x, b4.x), 0.f);
    r.y = fmaxf(fmaf(dv, acc.y, b4.y), 0.f);
    r.z = fmaxf(fmaf(dv, acc.z, b4.z), 0.f);
    r.w = fmaxf(fmaf(dv, acc.w, b4.w), 0.f);
    *(float4*)&sh[g * 128 + f4] = r;
    __syncthreads();

    // out[v, lane] = bl[lane] + sum_j h3[j] * Wl[j*32 + lane]
    float o = bl[lane];
    const float* hrow = &sh[g * 128];
    #pragma unroll 8
    for (int j = 0; j < 128; ++j)
        o = fmaf(hrow[j], Wl[j * 32 + lane], o);
    out32[(size_t)v * 32 + lane] = o;
}

// ---------------- launch ----------------

extern "C" void kernel_launch(void* const* d_in, const int* in_sizes, int n_in,
                              void* d_out, int out_size, void* d_ws, size_t ws_size,
                              hipStream_t stream) {
    const float* x      = (const float*)d_in[0];
    const int*   ei     = (const int*)d_in[1];
    const int*   srcArr = ei;
    const int*   dstArr = ei + N_EDGES;
    const float* W1 = (const float*)d_in[2];
    const float* b1 = (const float*)d_in[3];
    const float* W2 = (const float*)d_in[4];
    const float* b2 = (const float*)d_in[5];
    const float* W3 = (const float*)d_in[6];
    const float* b3 = (const float*)d_in[7];
    const float* Wl = (const float*)d_in[8];
    const float* bl = (const float*)d_in[9];
    float* out = (float*)d_out;

    // workspace layout
    float* bufA  = (float*)d_ws;                       // N*128
    float* bufB  = bufA + (size_t)N_NODES * 128;       // N*128
    float* dinv  = bufB + (size_t)N_NODES * 128;       // N
    float* colw  = dinv + N_NODES;                     // E
    int*   col   = (int*)(colw + N_EDGES);             // E
    int*   cnt   = col + N_EDGES;                      // N   <- memset base
    int*   fill  = cnt + N_NODES;                      // N
    int*   total = fill + N_NODES;                     // 1
    int*   start = total + 1;                          // N

    hipMemsetAsync(cnt, 0, (size_t)(2 * N_NODES + 1) * sizeof(int), stream);
    count_edges <<<(N_EDGES + 255) / 256, 256, 0, stream>>>(dstArr, cnt);
    reserve_rows<<<(N_NODES + 255) / 256, 256, 0, stream>>>(cnt, start, total, dinv);
    csr_fill    <<<(N_EDGES + 255) / 256, 256, 0, stream>>>(srcArr, dstArr, start, fill, col, colw, dinv);

    gemm128<<<(N_NODES + 63) / 64, 256, 0, stream>>>(x, W1, bufA);
    gcn_aggregate<<<N_NODES / 8, 256, 0, stream>>>(bufA, start, cnt, col, colw, dinv, b1, bufB);
    gemm128<<<(N_NODES + 63) / 64, 256, 0, stream>>>(bufB, W2, bufA);
    gcn_aggregate<<<N_NODES / 8, 256, 0, stream>>>(bufA, start, cnt, col, colw, dinv, b2, bufB);
    gemm128<<<(N_NODES + 63) / 64, 256, 0, stream>>>(bufB, W3, bufA);
    gcn_aggregate_final<<<N_NODES / 8, 256, 0, stream>>>(bufA, start, cnt, col, colw, dinv, b3, Wl, bl, out);
}